// Round 5
// baseline (60.235 us; speedup 1.0000x reference)
//
#include <hip/hip_runtime.h>
#include <hip/hip_cooperative_groups.h>
#include <math.h>

namespace cg = cooperative_groups;

#define CDIV(a,b) (((a)+(b)-1)/(b))

// ctrl block layout (one 64B memset covers it):
//   f[0] = reg-loss partial,  f[1] = score partial,
//   i[2] = nnzCount,          i[3] = scores doneCount

// ---------------------------------------------------------------------------
// K_front: fused (a) sparse_v + per-row flag + nnz count  and
//                (b) sampled-row init (recomputes threshold rows) + reg partial.
// Block ranges: [0, nbFlag) do (a) — 16 nodes/block; [nbFlag, nbFlag+nbSamp) do (b).
__global__ __launch_bounds__(256) void k_front(
    const float* __restrict__ w, const float* __restrict__ s,
    const int* __restrict__ users, const int* __restrict__ pos,
    const int* __restrict__ neg,
    float* __restrict__ h0, int* __restrict__ rowNnz,
    float* __restrict__ samp, float* __restrict__ ctrlf,
    int N, int B, int nbFlag)
{
    __shared__ int shi[4];
    __shared__ float shf[4];
    const int tid = threadIdx.x;
    const float t = 1.0f / (1.0f + expf(-s[0]));
    if ((int)blockIdx.x < nbFlag) {
        int node = blockIdx.x * 16 + (tid >> 4);
        int l = tid & 15;
        int nodeC = node < N ? node : N - 1;
        size_t off = (size_t)nodeC * 64 + l * 4;
        float4 v = *(const float4*)(w + off);
        float4 r;
        r.x = copysignf(fmaxf(fabsf(v.x) - t, 0.0f), v.x);
        r.y = copysignf(fmaxf(fabsf(v.y) - t, 0.0f), v.y);
        r.z = copysignf(fmaxf(fabsf(v.z) - t, 0.0f), v.z);
        r.w = copysignf(fmaxf(fabsf(v.w) - t, 0.0f), v.w);
        int nz = (r.x != 0.0f) | (r.y != 0.0f) | (r.z != 0.0f) | (r.w != 0.0f);
        for (int m = 1; m < 16; m <<= 1) nz |= __shfl_xor(nz, m);  // row-uniform
        if (node < N) {
            if (nz) *(float4*)(h0 + off) = r;  // zero rows of h0 are never read
            if (l == 0) rowNnz[node] = nz;
        }
        int c = (node < N && l == 0) ? nz : 0;
        for (int m = 1; m < 64; m <<= 1) c += __shfl_xor(c, m);
        if ((tid & 63) == 0) shi[tid >> 6] = c;
        __syncthreads();
        if (tid == 0) {
            int tot = shi[0] + shi[1] + shi[2] + shi[3];
            if (tot) atomicAdd((int*)ctrlf + 2, tot);
        }
    } else {
        int j = ((int)blockIdx.x - nbFlag) * 16 + (tid >> 4);
        int l = tid & 15;
        float ss = 0.0f;
        if (j < 3 * B) {
            int idx = (j < B) ? users[j] : ((j < 2 * B) ? pos[j - B] : neg[j - 2 * B]);
            float4 e = *(const float4*)(w + (size_t)idx * 64 + l * 4);
            float4 r;
            r.x = copysignf(fmaxf(fabsf(e.x) - t, 0.0f), e.x);
            r.y = copysignf(fmaxf(fabsf(e.y) - t, 0.0f), e.y);
            r.z = copysignf(fmaxf(fabsf(e.z) - t, 0.0f), e.z);
            r.w = copysignf(fmaxf(fabsf(e.w) - t, 0.0f), e.w);
            *(float4*)(samp + (size_t)j * 64 + l * 4) = r;  // layer-0 term of acc
            ss = e.x * e.x + e.y * e.y + e.z * e.z + e.w * e.w;
        }
        for (int m = 1; m < 64; m <<= 1) ss += __shfl_xor(ss, m);
        if ((tid & 63) == 0) shf[tid >> 6] = ss;
        __syncthreads();
        if (tid == 0) atomicAdd(&ctrlf[0], shf[0] + shf[1] + shf[2] + shf[3]);
    }
}

// ---------------------------------------------------------------------------
// Device helpers for k_prop phases
__device__ inline void spmm_pass(const float* __restrict__ hin, float* __restrict__ hout,
                                 const int* __restrict__ rowptr,
                                 const int2* __restrict__ edgep,
                                 const int* __restrict__ rowNnz,  // null = no flag skip
                                 int N, int gtid, int gsize) {
    for (int g2 = gtid; g2 < N * 16; g2 += gsize) {
        int node = g2 >> 4, l = g2 & 15;
        int beg = rowptr[node], end = rowptr[node + 1];
        float4 acc = make_float4(0.f, 0.f, 0.f, 0.f);
        for (int k = beg; k < end; ++k) {
            int2 ep = edgep[k];
            if (rowNnz && !rowNnz[ep.x]) continue;  // uniform over 16-lane group
            float a = __int_as_float(ep.y);
            float4 v = *(const float4*)(hin + (size_t)ep.x * 64 + l * 4);
            acc.x = fmaf(a, v.x, acc.x);
            acc.y = fmaf(a, v.y, acc.y);
            acc.z = fmaf(a, v.z, acc.z);
            acc.w = fmaf(a, v.w, acc.w);
        }
        *(float4*)(hout + (size_t)node * 64 + l * 4) = acc;
    }
}

__device__ inline void samp_add_pass(const float* __restrict__ h,
                                     const int* __restrict__ users,
                                     const int* __restrict__ pos,
                                     const int* __restrict__ neg,
                                     float* __restrict__ samp, int B,
                                     int gtid, int gsize) {
    for (int g2 = gtid; g2 < 3 * B * 16; g2 += gsize) {
        int j = g2 >> 4, l = g2 & 15;
        int idx = (j < B) ? users[j] : ((j < 2 * B) ? pos[j - B] : neg[j - 2 * B]);
        float4 v = *(const float4*)(h + (size_t)idx * 64 + l * 4);
        float4 a = *(float4*)(samp + (size_t)j * 64 + l * 4);
        a.x += v.x; a.y += v.y; a.z += v.z; a.w += v.w;
        *(float4*)(samp + (size_t)j * 64 + l * 4) = a;
    }
}

// ---------------------------------------------------------------------------
// K_prop: cooperative fused propagation. When nnzCount==0 all blocks exit
// immediately (propagation output is all-zero and unobservable). Otherwise:
// P0 zero-deg, P1 hist, P2 scan (3 sub-phases), P3 scatter, P4..P7 SpMM x3
// with sampled-row accumulation. Assumes N <= 4096*1024 (chunkSums <= 4096).
__global__ __launch_bounds__(256) void k_prop(
    const int* __restrict__ src, const int* __restrict__ dst,
    int* __restrict__ deg, int* __restrict__ chunkSums,
    int* __restrict__ rowptr, int* __restrict__ cursor, float* __restrict__ dinv,
    int2* __restrict__ edgep, const float* __restrict__ h0,
    float* __restrict__ h1, float* __restrict__ h2,
    const int* __restrict__ rowNnz, const int* __restrict__ ctrli,
    const int* __restrict__ users, const int* __restrict__ pos,
    const int* __restrict__ neg, float* __restrict__ samp,
    int N, int E, int B)
{
    if (ctrli[2] == 0) return;   // uniform across the whole grid
    __shared__ int shA[4];
    cg::grid_group grid = cg::this_grid();
    const int tid = threadIdx.x;
    const int lane = tid & 63, wid = tid >> 6;
    const int gsize = gridDim.x * blockDim.x;
    const int gtid = blockIdx.x * blockDim.x + tid;
    const int nchunk = (N + 1023) >> 10;

    // P0: zero in-degree array
    for (int i = gtid; i < N; i += gsize) deg[i] = 0;
    grid.sync();

    // P1: in-degree histogram
    for (int e = gtid; e < E; e += gsize) atomicAdd(&deg[dst[e]], 1);
    grid.sync();

    // P2a: per-chunk sums (CHUNK = 1024 = 256 thr x 4)
    for (int c = blockIdx.x; c < nchunk; c += gridDim.x) {
        int base = (c << 10) + tid * 4;
        int sum = 0;
        if (base + 3 < N) {
            int4 v = *(const int4*)(deg + base);
            sum = v.x + v.y + v.z + v.w;
        } else {
            for (int k = 0; k < 4; ++k) if (base + k < N) sum += deg[base + k];
        }
        for (int m = 1; m < 64; m <<= 1) sum += __shfl_xor(sum, m);
        __syncthreads();
        if (lane == 0) shA[wid] = sum;
        __syncthreads();
        if (tid == 0) chunkSums[c] = shA[0] + shA[1] + shA[2] + shA[3];
    }
    grid.sync();

    // P2b: block 0 exclusive-scans chunkSums in place (nchunk <= 1024 handled
    // by 256 thr x 4); also rowptr[N] = total
    if (blockIdx.x == 0) {
        int c0 = tid * 4;
        int a0 = (c0 + 0 < nchunk) ? chunkSums[c0 + 0] : 0;
        int a1 = (c0 + 1 < nchunk) ? chunkSums[c0 + 1] : 0;
        int a2 = (c0 + 2 < nchunk) ? chunkSums[c0 + 2] : 0;
        int a3 = (c0 + 3 < nchunk) ? chunkSums[c0 + 3] : 0;
        int tot = a0 + a1 + a2 + a3;
        int incl = tot;
        for (int off = 1; off < 64; off <<= 1) {
            int tt = __shfl_up(incl, off);
            if (lane >= off) incl += tt;
        }
        __syncthreads();
        if (lane == 63) shA[wid] = incl;
        __syncthreads();
        int wp = 0;
        for (int w = 0; w < wid; ++w) wp += shA[w];
        int excl = wp + incl - tot;
        if (c0 + 0 < nchunk) chunkSums[c0 + 0] = excl;
        if (c0 + 1 < nchunk) chunkSums[c0 + 1] = excl + a0;
        if (c0 + 2 < nchunk) chunkSums[c0 + 2] = excl + a0 + a1;
        if (c0 + 3 < nchunk) chunkSums[c0 + 3] = excl + a0 + a1 + a2;
        if (tid == 255) rowptr[N] = wp + incl;
    }
    grid.sync();

    // P2c: per-chunk local scan + chunk offset -> rowptr, cursor, dinv
    for (int c = blockIdx.x; c < nchunk; c += gridDim.x) {
        int base = (c << 10) + tid * 4;
        int v0 = 0, v1 = 0, v2 = 0, v3 = 0;
        if (base + 3 < N) {
            int4 v = *(const int4*)(deg + base);
            v0 = v.x; v1 = v.y; v2 = v.z; v3 = v.w;
        } else {
            if (base + 0 < N) v0 = deg[base + 0];
            if (base + 1 < N) v1 = deg[base + 1];
            if (base + 2 < N) v2 = deg[base + 2];
        }
        int tot = v0 + v1 + v2 + v3;
        int incl = tot;
        for (int off = 1; off < 64; off <<= 1) {
            int tt = __shfl_up(incl, off);
            if (lane >= off) incl += tt;
        }
        __syncthreads();
        if (lane == 63) shA[wid] = incl;
        __syncthreads();
        int wp = 0;
        for (int w = 0; w < wid; ++w) wp += shA[w];
        int excl = chunkSums[c] + wp + incl - tot;
        int e0 = excl, e1 = e0 + v0, e2 = e1 + v1, e3 = e2 + v2;
        if (base + 0 < N) { rowptr[base+0] = e0; cursor[base+0] = e0; dinv[base+0] = v0 > 0 ? rsqrtf((float)v0) : 0.f; }
        if (base + 1 < N) { rowptr[base+1] = e1; cursor[base+1] = e1; dinv[base+1] = v1 > 0 ? rsqrtf((float)v1) : 0.f; }
        if (base + 2 < N) { rowptr[base+2] = e2; cursor[base+2] = e2; dinv[base+2] = v2 > 0 ? rsqrtf((float)v2) : 0.f; }
        if (base + 3 < N) { rowptr[base+3] = e3; cursor[base+3] = e3; dinv[base+3] = v3 > 0 ? rsqrtf((float)v3) : 0.f; }
    }
    grid.sync();

    // P3: scatter edges into CSR order; payload packed 8B = (src, adj)
    for (int e = gtid; e < E; e += gsize) {
        int d = dst[e], sN = src[e];
        int k = atomicAdd(&cursor[d], 1);
        edgep[k] = make_int2(sN, __float_as_int(dinv[sN] * dinv[d]));
    }
    grid.sync();

    // P4: layer 0 SpMM (flag-guarded: h0 zero rows were never written)
    spmm_pass(h0, h1, rowptr, edgep, rowNnz, N, gtid, gsize);
    grid.sync();
    // P5: samp += h1 ; layer 1 SpMM h1 -> h2   (both only read h1)
    samp_add_pass(h1, users, pos, neg, samp, B, gtid, gsize);
    spmm_pass(h1, h2, rowptr, edgep, nullptr, N, gtid, gsize);
    grid.sync();
    // P6: samp += h2 ; layer 2 SpMM h2 -> h1   (h1 readers finished at sync)
    samp_add_pass(h2, users, pos, neg, samp, B, gtid, gsize);
    spmm_pass(h2, h1, rowptr, edgep, nullptr, N, gtid, gsize);
    grid.sync();
    // P7: samp += h1
    samp_add_pass(h1, users, pos, neg, samp, B, gtid, gsize);
}

// ---------------------------------------------------------------------------
// K_scores_final: BPR softplus partial per block + last-block finalize
__global__ __launch_bounds__(256) void k_scores_final(
    const float* __restrict__ samp, float* __restrict__ ctrlf,
    const float* __restrict__ s, float* __restrict__ out, int B, int nblocks)
{
    __shared__ float shf[4];
    int tid = threadIdx.x;
    int g = blockIdx.x * blockDim.x + tid;
    int j = g >> 4, l = g & 15;
    float sp = 0.0f;
    if (j < B) {
        float4 u = *(const float4*)(samp + (size_t)j * 64 + l * 4);
        float4 p = *(const float4*)(samp + (size_t)(j + B) * 64 + l * 4);
        float4 q = *(const float4*)(samp + (size_t)(j + 2 * B) * 64 + l * 4);
        float ps = u.x * p.x + u.y * p.y + u.z * p.z + u.w * p.w;
        float ns = u.x * q.x + u.y * q.y + u.z * q.z + u.w * q.w;
        for (int m = 1; m < 16; m <<= 1) {
            ps += __shfl_xor(ps, m);
            ns += __shfl_xor(ns, m);
        }
        if (l == 0) {
            float x = (ns - ps) * 0.0625f;  // all_emb = acc/4 -> score scale 1/16
            sp = fmaxf(x, 0.0f) + log1pf(expf(-fabsf(x)));  // stable softplus
        }
    }
    for (int m = 1; m < 64; m <<= 1) sp += __shfl_xor(sp, m);
    if ((tid & 63) == 0) shf[tid >> 6] = sp;
    __syncthreads();
    if (tid == 0) {
        atomicAdd(&ctrlf[1], shf[0] + shf[1] + shf[2] + shf[3]);
        __threadfence();
        int done = atomicAdd((int*)ctrlf + 3, 1);
        if (done == nblocks - 1) {
            __threadfence();
            float b = (float)B;
            float loss_emb = atomicAdd(&ctrlf[1], 0.0f) / b;  // coherent read
            float reg_loss = 0.5f * atomicAdd(&ctrlf[0], 0.0f) / b * 1e-4f;
            float s0 = s[0];
            float s_loss = 0.5f * s0 * s0 / b * 1e-4f;
            out[0] = loss_emb + reg_loss + s_loss;
            out[1] = loss_emb;
            out[2] = reg_loss;
            out[3] = s_loss;
        }
    }
}

// ---------------------------------------------------------------------------
extern "C" void kernel_launch(void* const* d_in, const int* in_sizes, int n_in,
                              void* d_out, int out_size, void* d_ws, size_t ws_size,
                              hipStream_t stream) {
    const float* weight = (const float*)d_in[0];
    const float* s      = (const float*)d_in[1];
    const int*   src    = (const int*)d_in[2];
    const int*   dst    = (const int*)d_in[3];
    const int*   users  = (const int*)d_in[4];
    const int*   pos    = (const int*)d_in[5];
    const int*   neg    = (const int*)d_in[6];

    const int D = 64;
    const int N = in_sizes[0] / D;
    const int E = in_sizes[2];
    const int B = in_sizes[4];

    char* wp = (char*)d_ws;
    auto alloc = [&](size_t bytes) -> void* {
        void* p = (void*)wp;
        wp += (bytes + 255) & ~(size_t)255;
        return p;
    };
    int*   deg      = (int*)alloc((size_t)N * 4);
    float* dinv     = (float*)alloc((size_t)N * 4);
    int*   rowptr   = (int*)alloc((size_t)(N + 1) * 4);
    int*   cursor   = (int*)alloc((size_t)N * 4);
    int*   rowNnz   = (int*)alloc((size_t)N * 4);
    int*   chunkSums= (int*)alloc((size_t)4096 * 4);
    int2*  edgep    = (int2*)alloc((size_t)E * 8);
    float* h0       = (float*)alloc((size_t)N * D * 4);
    float* h1       = (float*)alloc((size_t)N * D * 4);
    float* h2       = (float*)alloc((size_t)N * D * 4);
    float* samp     = (float*)alloc((size_t)3 * B * D * 4);
    float* ctrlf    = (float*)alloc(256);

    hipMemsetAsync(ctrlf, 0, 64, stream);

    const int nbFlag = CDIV(N, 16);
    const int nbSamp = CDIV(3 * B, 16);
    k_front<<<nbFlag + nbSamp, 256, 0, stream>>>(weight, s, users, pos, neg,
                                                 h0, rowNnz, samp, ctrlf, N, B, nbFlag);

    // exact-typed locals for cooperative arg passing
    const float* h0c = h0;
    const int* rowNnzC = rowNnz;
    const int* ctrli = (const int*)ctrlf;
    int Nv = N, Ev = E, Bv = B;
    void* kargs[] = {
        (void*)&src, (void*)&dst, (void*)&deg, (void*)&chunkSums,
        (void*)&rowptr, (void*)&cursor, (void*)&dinv, (void*)&edgep,
        (void*)&h0c, (void*)&h1, (void*)&h2, (void*)&rowNnzC, (void*)&ctrli,
        (void*)&users, (void*)&pos, (void*)&neg, (void*)&samp,
        (void*)&Nv, (void*)&Ev, (void*)&Bv
    };
    hipLaunchCooperativeKernel((void*)k_prop, dim3(256), dim3(256), kargs, 0, stream);

    const int nbScore = CDIV(B * 16, 256);
    k_scores_final<<<nbScore, 256, 0, stream>>>(samp, ctrlf, s, (float*)d_out,
                                                B, nbScore);
}

// Round 6
// 47.780 us; speedup vs baseline: 1.2607x; 1.2607x over previous
//
#include <hip/hip_runtime.h>
#include <math.h>

#define CDIV(a,b) (((a)+(b)-1)/(b))
#define NBLK 256   // <= CU count (256): all blocks co-resident -> grid barrier safe
#define TPB  256

// ---------------------------------------------------------------------------
// Hand-rolled grid barrier: per-barrier arrive counter (zeroed by memset each
// call), device-scope fences for cross-XCD visibility. Requires all NBLK
// blocks resident (NBLK <= #CUs, tiny footprint -> guaranteed).
__device__ inline void gbar(int* __restrict__ cnts, int k) {
    __syncthreads();
    if (threadIdx.x == 0) {
        __threadfence();                       // release: flush writes
        atomicAdd(&cnts[k], 1);
        while (atomicAdd(&cnts[k], 0) < NBLK) __builtin_amdgcn_s_sleep(2);
        __threadfence();                       // acquire: invalidate stale lines
    }
    __syncthreads();
}

// ---------------------------------------------------------------------------
__global__ __launch_bounds__(TPB) void k_mega(
    const float* __restrict__ weight, const float* __restrict__ s,
    const int* __restrict__ src, const int* __restrict__ dst,
    const int* __restrict__ users, const int* __restrict__ pos,
    const int* __restrict__ neg,
    int* __restrict__ cnts, int* __restrict__ nnzSlots,
    float* __restrict__ regSlots, float* __restrict__ spSlots,
    int* __restrict__ deg, int* __restrict__ chunkSums,
    int* __restrict__ rowptr, int* __restrict__ cursor, float* __restrict__ dinv,
    int2* __restrict__ edgep, float* __restrict__ h0,
    float* __restrict__ h1, float* __restrict__ h2, int* __restrict__ rowNnz,
    float* __restrict__ out, int N, int E, int B)
{
    __shared__ float sampT[48 * 64];  // 16 samples x {u,p,n} x 64 dims (nnz path)
    __shared__ int   shi[4];
    __shared__ float shf[4];
    const int tid  = threadIdx.x;
    const int b    = blockIdx.x;
    const int lane = tid & 63, wid = tid >> 6;
    const int l16  = tid & 15;
    const float t  = 1.0f / (1.0f + expf(-s[0]));
    const int gsize = NBLK * TPB;
    const int gtid  = b * TPB + tid;

    // ---- Phase A1: soft-threshold flags over a contiguous row strip --------
    // h0 written ONLY for nonzero rows (zero rows are never read downstream:
    // layer-0 SpMM skips them via rowNnz).
    {
        int rpb = CDIV(N, NBLK);
        int r0 = b * rpb;
        int r1 = r0 + rpb; if (r1 > N) r1 = N;
        int nzc = 0;
        for (int r = r0 + (tid >> 4); r < r1; r += 16) {
            size_t off = (size_t)r * 64 + l16 * 4;
            float4 v = *(const float4*)(weight + off);
            float4 rr;
            rr.x = copysignf(fmaxf(fabsf(v.x) - t, 0.0f), v.x);
            rr.y = copysignf(fmaxf(fabsf(v.y) - t, 0.0f), v.y);
            rr.z = copysignf(fmaxf(fabsf(v.z) - t, 0.0f), v.z);
            rr.w = copysignf(fmaxf(fabsf(v.w) - t, 0.0f), v.w);
            int nz = (rr.x != 0.0f) | (rr.y != 0.0f) | (rr.z != 0.0f) | (rr.w != 0.0f);
            for (int m = 1; m < 16; m <<= 1) nz |= __shfl_xor(nz, m);  // row-uniform
            if (nz) *(float4*)(h0 + off) = rr;
            if (l16 == 0) { rowNnz[r] = nz; nzc += nz; }
        }
        for (int m = 1; m < 64; m <<= 1) nzc += __shfl_xor(nzc, m);
        __syncthreads();
        if (lane == 0) shi[wid] = nzc;
        __syncthreads();
        if (tid == 0) nnzSlots[b] = shi[0] + shi[1] + shi[2] + shi[3];
    }

    // ---- Phase A2: reg-loss partial over this block's sampled-row strip ----
    {
        int spb = CDIV(3 * B, NBLK);
        int j0 = b * spb;
        int j1 = j0 + spb; if (j1 > 3 * B) j1 = 3 * B;
        float ss = 0.0f;
        for (int j = j0 + (tid >> 4); j < j1; j += 16) {
            int idx = (j < B) ? users[j] : ((j < 2 * B) ? pos[j - B] : neg[j - 2 * B]);
            float4 e = *(const float4*)(weight + (size_t)idx * 64 + l16 * 4);
            ss += e.x * e.x + e.y * e.y + e.z * e.z + e.w * e.w;
        }
        for (int m = 1; m < 64; m <<= 1) ss += __shfl_xor(ss, m);
        __syncthreads();
        if (lane == 0) shf[wid] = ss;
        __syncthreads();
        if (tid == 0) regSlots[b] = shf[0] + shf[1] + shf[2] + shf[3];
    }

    gbar(cnts, 0);

    // ---- Gate: total nonzero rows (every block computes the same sum) ------
    int gv = (tid < NBLK) ? nnzSlots[tid] : 0;
    for (int m = 1; m < 64; m <<= 1) gv += __shfl_xor(gv, m);
    __syncthreads();
    if (lane == 0) shi[wid] = gv;
    __syncthreads();
    int gate = shi[0] + shi[1] + shi[2] + shi[3];

    if (gate == 0) {
        // sparse_v == 0 everywhere -> all sampled embeddings are 0 ->
        // pos_scores = neg_scores = 0 -> loss_emb = softplus(0) = ln 2 exactly.
        if (b == 0) {
            float rs = (tid < NBLK) ? regSlots[tid] : 0.0f;
            for (int m = 1; m < 64; m <<= 1) rs += __shfl_xor(rs, m);
            __syncthreads();
            if (lane == 0) shf[wid] = rs;
            __syncthreads();
            if (tid == 0) {
                float bm = (float)B;
                float reg_sum  = shf[0] + shf[1] + shf[2] + shf[3];
                float loss_emb = 0.69314718056f;
                float reg_loss = 0.5f * reg_sum / bm * 1e-4f;
                float s0 = s[0];
                float s_loss = 0.5f * s0 * s0 / bm * 1e-4f;
                out[0] = loss_emb + reg_loss + s_loss;
                out[1] = loss_emb;
                out[2] = reg_loss;
                out[3] = s_loss;
            }
        }
        return;
    }

    // =======================================================================
    // nnz > 0 path (assumes B <= NBLK*16 = 4096, fixed by this problem).
    // =======================================================================
    const int sb = b * 16;  // first sample owned by this block

    // samp tile init in LDS: rows 0..15=u, 16..31=p, 32..47=n (layer-0 term)
    for (int m2 = tid >> 4; m2 < 48; m2 += 16) {
        int kind = m2 >> 4, k = m2 & 15;
        int gj = sb + k;
        float4 rr = make_float4(0.f, 0.f, 0.f, 0.f);
        if (gj < B) {
            int idx = kind == 0 ? users[gj] : kind == 1 ? pos[gj] : neg[gj];
            float4 e = *(const float4*)(weight + (size_t)idx * 64 + l16 * 4);
            rr.x = copysignf(fmaxf(fabsf(e.x) - t, 0.0f), e.x);
            rr.y = copysignf(fmaxf(fabsf(e.y) - t, 0.0f), e.y);
            rr.z = copysignf(fmaxf(fabsf(e.z) - t, 0.0f), e.z);
            rr.w = copysignf(fmaxf(fabsf(e.w) - t, 0.0f), e.w);
        }
        *(float4*)(&sampT[m2 * 64 + l16 * 4]) = rr;
    }

    // P0: zero in-degree
    for (int i = gtid; i < N; i += gsize) deg[i] = 0;
    gbar(cnts, 1);
    // P1: histogram
    for (int e = gtid; e < E; e += gsize) atomicAdd(&deg[dst[e]], 1);
    gbar(cnts, 2);

    // P2a: per-chunk sums (chunk = 1024 = 256 thr x 4); nchunk <= 1024 (N<=1M)
    const int nchunk = (N + 1023) >> 10;
    for (int c = b; c < nchunk; c += NBLK) {
        int base = (c << 10) + tid * 4;
        int sum = 0;
        if (base + 3 < N) {
            int4 v = *(const int4*)(deg + base);
            sum = v.x + v.y + v.z + v.w;
        } else {
            for (int k = 0; k < 4; ++k) if (base + k < N) sum += deg[base + k];
        }
        for (int m = 1; m < 64; m <<= 1) sum += __shfl_xor(sum, m);
        __syncthreads();
        if (lane == 0) shi[wid] = sum;
        __syncthreads();
        if (tid == 0) chunkSums[c] = shi[0] + shi[1] + shi[2] + shi[3];
    }
    gbar(cnts, 3);

    // P2b: block 0 exclusive-scans chunkSums in place; rowptr[N] = total
    if (b == 0) {
        int c0 = tid * 4;
        int a0 = (c0 + 0 < nchunk) ? chunkSums[c0 + 0] : 0;
        int a1 = (c0 + 1 < nchunk) ? chunkSums[c0 + 1] : 0;
        int a2 = (c0 + 2 < nchunk) ? chunkSums[c0 + 2] : 0;
        int a3 = (c0 + 3 < nchunk) ? chunkSums[c0 + 3] : 0;
        int tot = a0 + a1 + a2 + a3;
        int incl = tot;
        for (int off = 1; off < 64; off <<= 1) {
            int tt = __shfl_up(incl, off);
            if (lane >= off) incl += tt;
        }
        __syncthreads();
        if (lane == 63) shi[wid] = incl;
        __syncthreads();
        int wp = 0;
        for (int w = 0; w < wid; ++w) wp += shi[w];
        int excl = wp + incl - tot;
        if (c0 + 0 < nchunk) chunkSums[c0 + 0] = excl;
        if (c0 + 1 < nchunk) chunkSums[c0 + 1] = excl + a0;
        if (c0 + 2 < nchunk) chunkSums[c0 + 2] = excl + a0 + a1;
        if (c0 + 3 < nchunk) chunkSums[c0 + 3] = excl + a0 + a1 + a2;
        if (tid == 0) rowptr[N] = shi[0] + shi[1] + shi[2] + shi[3];
    }
    gbar(cnts, 4);

    // P2c: per-chunk local scan + chunk offset -> rowptr, cursor, dinv
    for (int c = b; c < nchunk; c += NBLK) {
        int base = (c << 10) + tid * 4;
        int v0 = 0, v1 = 0, v2 = 0, v3 = 0;
        if (base + 3 < N) {
            int4 v = *(const int4*)(deg + base);
            v0 = v.x; v1 = v.y; v2 = v.z; v3 = v.w;
        } else {
            if (base + 0 < N) v0 = deg[base + 0];
            if (base + 1 < N) v1 = deg[base + 1];
            if (base + 2 < N) v2 = deg[base + 2];
        }
        int tot = v0 + v1 + v2 + v3;
        int incl = tot;
        for (int off = 1; off < 64; off <<= 1) {
            int tt = __shfl_up(incl, off);
            if (lane >= off) incl += tt;
        }
        __syncthreads();
        if (lane == 63) shi[wid] = incl;
        __syncthreads();
        int wp = 0;
        for (int w = 0; w < wid; ++w) wp += shi[w];
        int excl = chunkSums[c] + wp + incl - tot;
        int e0 = excl, e1 = e0 + v0, e2 = e1 + v1, e3 = e2 + v2;
        if (base + 0 < N) { rowptr[base+0] = e0; cursor[base+0] = e0; dinv[base+0] = v0 > 0 ? rsqrtf((float)v0) : 0.f; }
        if (base + 1 < N) { rowptr[base+1] = e1; cursor[base+1] = e1; dinv[base+1] = v1 > 0 ? rsqrtf((float)v1) : 0.f; }
        if (base + 2 < N) { rowptr[base+2] = e2; cursor[base+2] = e2; dinv[base+2] = v2 > 0 ? rsqrtf((float)v2) : 0.f; }
        if (base + 3 < N) { rowptr[base+3] = e3; cursor[base+3] = e3; dinv[base+3] = v3 > 0 ? rsqrtf((float)v3) : 0.f; }
    }
    gbar(cnts, 5);

    // P3: scatter edges into CSR order; payload packed 8B = (src, adj)
    for (int e = gtid; e < E; e += gsize) {
        int d = dst[e], sN = src[e];
        int k = atomicAdd(&cursor[d], 1);
        edgep[k] = make_int2(sN, __float_as_int(dinv[sN] * dinv[d]));
    }
    gbar(cnts, 6);

    // SpMM helper lambda (grid-stride over node*16 lanes-of-4)
    auto spmm = [&](const float* hin, float* hout, const int* flags) {
        for (int g2 = gtid; g2 < N * 16; g2 += gsize) {
            int node = g2 >> 4, l = g2 & 15;
            int beg = rowptr[node], end = rowptr[node + 1];
            float4 acc = make_float4(0.f, 0.f, 0.f, 0.f);
            for (int k = beg; k < end; ++k) {
                int2 ep = edgep[k];
                if (flags && !flags[ep.x]) continue;
                float a = __int_as_float(ep.y);
                float4 v = *(const float4*)(hin + (size_t)ep.x * 64 + l * 4);
                acc.x = fmaf(a, v.x, acc.x);
                acc.y = fmaf(a, v.y, acc.y);
                acc.z = fmaf(a, v.z, acc.z);
                acc.w = fmaf(a, v.w, acc.w);
            }
            *(float4*)(hout + (size_t)node * 64 + l * 4) = acc;
        }
    };
    auto samp_add = [&](const float* h) {
        for (int m2 = tid >> 4; m2 < 48; m2 += 16) {
            int kind = m2 >> 4, k = m2 & 15;
            int gj = sb + k;
            if (gj < B) {
                int idx = kind == 0 ? users[gj] : kind == 1 ? pos[gj] : neg[gj];
                float4 v = *(const float4*)(h + (size_t)idx * 64 + l16 * 4);
                float* p = &sampT[m2 * 64 + l16 * 4];
                p[0] += v.x; p[1] += v.y; p[2] += v.z; p[3] += v.w;
            }
        }
    };

    // P4: layer 0 (flag-guarded: zero rows of h0 were never written)
    spmm(h0, h1, rowNnz);
    gbar(cnts, 7);
    // P5: samp += h1 ; layer 1: h1 -> h2
    samp_add(h1);
    spmm(h1, h2, nullptr);
    gbar(cnts, 8);
    // P6: samp += h2 ; layer 2: h2 -> h1
    samp_add(h2);
    spmm(h2, h1, nullptr);
    gbar(cnts, 9);
    // P7: samp += h1
    samp_add(h1);
    __syncthreads();

    // Scores from LDS: 16 thr per sample
    {
        int k = tid >> 4;
        float sp = 0.0f;
        int gj = sb + k;
        if (gj < B) {
            float4 u = *(const float4*)(&sampT[(0 * 16 + k) * 64 + l16 * 4]);
            float4 p = *(const float4*)(&sampT[(1 * 16 + k) * 64 + l16 * 4]);
            float4 q = *(const float4*)(&sampT[(2 * 16 + k) * 64 + l16 * 4]);
            float ps = u.x * p.x + u.y * p.y + u.z * p.z + u.w * p.w;
            float ns = u.x * q.x + u.y * q.y + u.z * q.z + u.w * q.w;
            for (int m = 1; m < 16; m <<= 1) {
                ps += __shfl_xor(ps, m);
                ns += __shfl_xor(ns, m);
            }
            if (l16 == 0) {
                float x = (ns - ps) * 0.0625f;  // all_emb = acc/4 -> scale 1/16
                sp = fmaxf(x, 0.0f) + log1pf(expf(-fabsf(x)));
            }
        }
        for (int m = 1; m < 64; m <<= 1) sp += __shfl_xor(sp, m);
        __syncthreads();
        if (lane == 0) shf[wid] = sp;
        __syncthreads();
        if (tid == 0) spSlots[b] = shf[0] + shf[1] + shf[2] + shf[3];
    }
    gbar(cnts, 10);

    if (b == 0) {
        float sp = (tid < NBLK) ? spSlots[tid] : 0.0f;
        for (int m = 1; m < 64; m <<= 1) sp += __shfl_xor(sp, m);
        __syncthreads();
        if (lane == 0) shf[wid] = sp;
        __syncthreads();
        float sp_sum = shf[0] + shf[1] + shf[2] + shf[3];
        __syncthreads();
        float rs = (tid < NBLK) ? regSlots[tid] : 0.0f;
        for (int m = 1; m < 64; m <<= 1) rs += __shfl_xor(rs, m);
        __syncthreads();
        if (lane == 0) shf[wid] = rs;
        __syncthreads();
        if (tid == 0) {
            float bm = (float)B;
            float reg_sum  = shf[0] + shf[1] + shf[2] + shf[3];
            float loss_emb = sp_sum / bm;
            float reg_loss = 0.5f * reg_sum / bm * 1e-4f;
            float s0 = s[0];
            float s_loss = 0.5f * s0 * s0 / bm * 1e-4f;
            out[0] = loss_emb + reg_loss + s_loss;
            out[1] = loss_emb;
            out[2] = reg_loss;
            out[3] = s_loss;
        }
    }
}

// ---------------------------------------------------------------------------
extern "C" void kernel_launch(void* const* d_in, const int* in_sizes, int n_in,
                              void* d_out, int out_size, void* d_ws, size_t ws_size,
                              hipStream_t stream) {
    const float* weight = (const float*)d_in[0];
    const float* s      = (const float*)d_in[1];
    const int*   src    = (const int*)d_in[2];
    const int*   dst    = (const int*)d_in[3];
    const int*   users  = (const int*)d_in[4];
    const int*   pos    = (const int*)d_in[5];
    const int*   neg    = (const int*)d_in[6];

    const int D = 64;
    const int N = in_sizes[0] / D;
    const int E = in_sizes[2];
    const int B = in_sizes[4];

    char* wp = (char*)d_ws;
    auto alloc = [&](size_t bytes) -> void* {
        void* p = (void*)wp;
        wp += (bytes + 255) & ~(size_t)255;
        return p;
    };
    int*   cnts     = (int*)alloc(128);            // 32 barrier counters
    int*   nnzSlots = (int*)alloc((size_t)NBLK * 4);
    float* regSlots = (float*)alloc((size_t)NBLK * 4);
    float* spSlots  = (float*)alloc((size_t)NBLK * 4);
    int*   deg      = (int*)alloc((size_t)N * 4);
    int*   chunkSums= (int*)alloc((size_t)4096 * 4);
    int*   rowptr   = (int*)alloc((size_t)(N + 1) * 4);
    int*   cursor   = (int*)alloc((size_t)N * 4);
    float* dinv     = (float*)alloc((size_t)N * 4);
    int*   rowNnz   = (int*)alloc((size_t)N * 4);
    int2*  edgep    = (int2*)alloc((size_t)E * 8);
    float* h0       = (float*)alloc((size_t)N * D * 4);
    float* h1       = (float*)alloc((size_t)N * D * 4);
    float* h2       = (float*)alloc((size_t)N * D * 4);

    hipMemsetAsync(cnts, 0, 128, stream);
    k_mega<<<NBLK, TPB, 0, stream>>>(weight, s, src, dst, users, pos, neg,
                                     cnts, nnzSlots, regSlots, spSlots,
                                     deg, chunkSums, rowptr, cursor, dinv,
                                     edgep, h0, h1, h2, rowNnz,
                                     (float*)d_out, N, E, B);
}

// Round 7
// 32.222 us; speedup vs baseline: 1.8694x; 1.4829x over previous
//
#include <hip/hip_runtime.h>
#include <math.h>

#define CDIV(a,b) (((a)+(b)-1)/(b))
#define NBLK 256   // <= CU count: all blocks co-resident (256 CUs) -> grid barrier safe
#define TPB  1024
#define NWAVE (TPB / 64)

// ctrl layout (int index), zeroed by one 256B memset per call:
//   [0..15]  barrier counters
//   [16]     nnzTotal (int)
//   [17]     regTotal (float)
//   [18]     spTotal  (float)

__device__ inline void gbar(int* __restrict__ cnts, int k) {
    __syncthreads();
    if (threadIdx.x == 0) {
        __threadfence();                      // release
        atomicAdd(&cnts[k], 1);
        while (atomicAdd(&cnts[k], 0) < NBLK) __builtin_amdgcn_s_sleep(2);
        __threadfence();                      // acquire
    }
    __syncthreads();
}

// ---------------------------------------------------------------------------
__global__ __launch_bounds__(TPB) void k_mega(
    const float* __restrict__ weight, const float* __restrict__ s,
    const int* __restrict__ src, const int* __restrict__ dst,
    const int* __restrict__ users, const int* __restrict__ pos,
    const int* __restrict__ neg,
    int* __restrict__ ctrl,
    int* __restrict__ deg, int* __restrict__ chunkSums,
    int* __restrict__ rowptr, int* __restrict__ cursor, float* __restrict__ dinv,
    int2* __restrict__ edgep, float* __restrict__ h0,
    float* __restrict__ h1, float* __restrict__ h2, int* __restrict__ rowNnz,
    float* __restrict__ out, int N, int E, int B)
{
    __shared__ float sampT[48 * 64];   // 16 samples x {u,p,n} x 64 dims (nnz path)
    __shared__ int   shi[NWAVE];
    __shared__ float shf[NWAVE];
    __shared__ int   gateS;
    const int tid  = threadIdx.x;
    const int b    = blockIdx.x;
    const int lane = tid & 63, wid = tid >> 6;
    const int gsize = NBLK * TPB;
    const int gtid  = b * TPB + tid;
    const float t  = 1.0f / (1.0f + expf(-s[0]));
    int*   nnzTotal = ctrl + 16;
    float* regTotal = (float*)(ctrl + 17);
    float* spTotal  = (float*)(ctrl + 18);

    const float4* __restrict__ wf4  = (const float4*)weight;
    float4* __restrict__       h0f4 = (float4*)h0;

    // ---- Phase A1: soft-threshold scan (flat float4 index, ballot row flags)
    int   nzc = 0;
    float ss  = 0.0f;
    {
        const int total = N * 16;     // float4 elements; multiple of 16
        const int grp16 = (lane >> 4) << 4;   // my 16-lane row-group base bit
        auto proc = [&](int idx, float4 v) {
            float4 r;
            r.x = copysignf(fmaxf(fabsf(v.x) - t, 0.0f), v.x);
            r.y = copysignf(fmaxf(fabsf(v.y) - t, 0.0f), v.y);
            r.z = copysignf(fmaxf(fabsf(v.z) - t, 0.0f), v.z);
            r.w = copysignf(fmaxf(fabsf(v.w) - t, 0.0f), v.w);
            int nzl = (r.x != 0.0f) | (r.y != 0.0f) | (r.z != 0.0f) | (r.w != 0.0f);
            unsigned long long m = __ballot(nzl);
            int rowm = (int)((m >> grp16) & 0xFFFFull);   // row-uniform
            if (rowm) h0f4[idx] = r;
            if ((idx & 15) == 0) { rowNnz[idx >> 4] = (rowm != 0); nzc += (rowm != 0); }
        };
        int idx = gtid;
        while (idx + 3 * gsize < total) {      // 4-deep independent loads
            float4 a0 = wf4[idx];
            float4 a1 = wf4[idx + gsize];
            float4 a2 = wf4[idx + 2 * gsize];
            float4 a3 = wf4[idx + 3 * gsize];
            proc(idx, a0); proc(idx + gsize, a1);
            proc(idx + 2 * gsize, a2); proc(idx + 3 * gsize, a3);
            idx += 4 * gsize;
        }
        while (idx + gsize < total) {          // 2-deep
            float4 a0 = wf4[idx];
            float4 a1 = wf4[idx + gsize];
            proc(idx, a0); proc(idx + gsize, a1);
            idx += 2 * gsize;
        }
        if (idx < total) { float4 a0 = wf4[idx]; proc(idx, a0); }
    }

    // ---- Phase A2: reg-loss gather (one sample-row float4 per thread) ------
    {
        int tot = 3 * B * 16;
        for (int g2 = gtid; g2 < tot; g2 += gsize) {
            int j = g2 >> 4, l16 = g2 & 15;
            int idx = (j < B) ? users[j] : ((j < 2 * B) ? pos[j - B] : neg[j - 2 * B]);
            float4 e = *(const float4*)(weight + (size_t)idx * 64 + l16 * 4);
            ss += e.x * e.x + e.y * e.y + e.z * e.z + e.w * e.w;
        }
    }

    // block reduce nzc, ss -> global atomics
    for (int m = 1; m < 64; m <<= 1) {
        nzc += __shfl_xor(nzc, m);
        ss  += __shfl_xor(ss, m);
    }
    if (lane == 0) { shi[wid] = nzc; shf[wid] = ss; }
    __syncthreads();
    if (tid == 0) {
        int   a = 0; float f = 0.0f;
        for (int i = 0; i < NWAVE; ++i) { a += shi[i]; f += shf[i]; }
        if (a) atomicAdd(nnzTotal, a);
        atomicAdd(regTotal, f);
    }

    gbar(ctrl, 0);

    if (tid == 0) gateS = atomicAdd(nnzTotal, 0);
    __syncthreads();
    if (gateS == 0) {
        // sparse_v == 0 everywhere -> sampled embeddings 0 -> scores 0 ->
        // loss_emb = softplus(0) = ln 2 exactly.
        if (b == 0 && tid == 0) {
            float bm = (float)B;
            float loss_emb = 0.69314718056f;
            float reg_loss = 0.5f * atomicAdd(regTotal, 0.0f) / bm * 1e-4f;
            float s0 = s[0];
            float s_loss = 0.5f * s0 * s0 / bm * 1e-4f;
            out[0] = loss_emb + reg_loss + s_loss;
            out[1] = loss_emb;
            out[2] = reg_loss;
            out[3] = s_loss;
        }
        return;
    }

    // =======================================================================
    // nnz > 0 path (B <= NBLK*16 = 4096 fixed by this problem)
    // =======================================================================
    const int sb = b * 16;
    const int l16 = tid & 15;

    // samp tile init in LDS: rows 0..15=u, 16..31=p, 32..47=n (layer-0 term)
    for (int m2 = tid >> 4; m2 < 48; m2 += TPB / 16) {
        int kind = m2 >> 4, k = m2 & 15;
        int gj = sb + k;
        float4 rr = make_float4(0.f, 0.f, 0.f, 0.f);
        if (gj < B) {
            int idx = kind == 0 ? users[gj] : kind == 1 ? pos[gj] : neg[gj];
            float4 e = *(const float4*)(weight + (size_t)idx * 64 + l16 * 4);
            rr.x = copysignf(fmaxf(fabsf(e.x) - t, 0.0f), e.x);
            rr.y = copysignf(fmaxf(fabsf(e.y) - t, 0.0f), e.y);
            rr.z = copysignf(fmaxf(fabsf(e.z) - t, 0.0f), e.z);
            rr.w = copysignf(fmaxf(fabsf(e.w) - t, 0.0f), e.w);
        }
        *(float4*)(&sampT[m2 * 64 + l16 * 4]) = rr;
    }

    // P0: zero in-degree
    for (int i = gtid; i < N; i += gsize) deg[i] = 0;
    gbar(ctrl, 1);
    // P1: histogram
    for (int e = gtid; e < E; e += gsize) atomicAdd(&deg[dst[e]], 1);
    gbar(ctrl, 2);

    // P2a: per-chunk sums (chunk = 4096 = 1024 thr x 4)
    const int nchunk = (N + 4095) >> 12;
    for (int c = b; c < nchunk; c += NBLK) {
        int base = (c << 12) + tid * 4;
        int sum = 0;
        if (base + 3 < N) {
            int4 v = *(const int4*)(deg + base);
            sum = v.x + v.y + v.z + v.w;
        } else {
            for (int k = 0; k < 4; ++k) if (base + k < N) sum += deg[base + k];
        }
        for (int m = 1; m < 64; m <<= 1) sum += __shfl_xor(sum, m);
        __syncthreads();
        if (lane == 0) shi[wid] = sum;
        __syncthreads();
        if (tid == 0) {
            int tt = 0;
            for (int w = 0; w < NWAVE; ++w) tt += shi[w];
            chunkSums[c] = tt;
        }
        __syncthreads();
    }
    gbar(ctrl, 3);

    // P2b: block 0 exclusive-scans chunkSums in place; rowptr[N] = total
    if (b == 0) {
        int c0 = tid * 4;
        int a0 = (c0 + 0 < nchunk) ? chunkSums[c0 + 0] : 0;
        int a1 = (c0 + 1 < nchunk) ? chunkSums[c0 + 1] : 0;
        int a2 = (c0 + 2 < nchunk) ? chunkSums[c0 + 2] : 0;
        int a3 = (c0 + 3 < nchunk) ? chunkSums[c0 + 3] : 0;
        int tot = a0 + a1 + a2 + a3;
        int incl = tot;
        for (int off = 1; off < 64; off <<= 1) {
            int tt = __shfl_up(incl, off);
            if (lane >= off) incl += tt;
        }
        __syncthreads();
        if (lane == 63) shi[wid] = incl;
        __syncthreads();
        int wp = 0;
        for (int w = 0; w < wid; ++w) wp += shi[w];
        int excl = wp + incl - tot;
        if (c0 + 0 < nchunk) chunkSums[c0 + 0] = excl;
        if (c0 + 1 < nchunk) chunkSums[c0 + 1] = excl + a0;
        if (c0 + 2 < nchunk) chunkSums[c0 + 2] = excl + a0 + a1;
        if (c0 + 3 < nchunk) chunkSums[c0 + 3] = excl + a0 + a1 + a2;
        if (tid == 0) {
            int tt = 0;
            for (int w = 0; w < NWAVE; ++w) tt += shi[w];
            rowptr[N] = tt;
        }
    }
    gbar(ctrl, 4);

    // P2c: per-chunk local scan + chunk offset -> rowptr, cursor, dinv
    for (int c = b; c < nchunk; c += NBLK) {
        int base = (c << 12) + tid * 4;
        int v0 = 0, v1 = 0, v2 = 0, v3 = 0;
        if (base + 3 < N) {
            int4 v = *(const int4*)(deg + base);
            v0 = v.x; v1 = v.y; v2 = v.z; v3 = v.w;
        } else {
            if (base + 0 < N) v0 = deg[base + 0];
            if (base + 1 < N) v1 = deg[base + 1];
            if (base + 2 < N) v2 = deg[base + 2];
        }
        int tot = v0 + v1 + v2 + v3;
        int incl = tot;
        for (int off = 1; off < 64; off <<= 1) {
            int tt = __shfl_up(incl, off);
            if (lane >= off) incl += tt;
        }
        __syncthreads();
        if (lane == 63) shi[wid] = incl;
        __syncthreads();
        int wp = 0;
        for (int w = 0; w < wid; ++w) wp += shi[w];
        int excl = chunkSums[c] + wp + incl - tot;
        int e0 = excl, e1 = e0 + v0, e2 = e1 + v1, e3 = e2 + v2;
        if (base + 0 < N) { rowptr[base+0] = e0; cursor[base+0] = e0; dinv[base+0] = v0 > 0 ? rsqrtf((float)v0) : 0.f; }
        if (base + 1 < N) { rowptr[base+1] = e1; cursor[base+1] = e1; dinv[base+1] = v1 > 0 ? rsqrtf((float)v1) : 0.f; }
        if (base + 2 < N) { rowptr[base+2] = e2; cursor[base+2] = e2; dinv[base+2] = v2 > 0 ? rsqrtf((float)v2) : 0.f; }
        if (base + 3 < N) { rowptr[base+3] = e3; cursor[base+3] = e3; dinv[base+3] = v3 > 0 ? rsqrtf((float)v3) : 0.f; }
        __syncthreads();
    }
    gbar(ctrl, 5);

    // P3: scatter edges into CSR order; payload packed 8B = (src, adj)
    for (int e = gtid; e < E; e += gsize) {
        int d = dst[e], sN = src[e];
        int k = atomicAdd(&cursor[d], 1);
        edgep[k] = make_int2(sN, __float_as_int(dinv[sN] * dinv[d]));
    }
    gbar(ctrl, 6);

    auto spmm = [&](const float* hin, float* hout, const int* flags) {
        for (int g2 = gtid; g2 < N * 16; g2 += gsize) {
            int node = g2 >> 4, l = g2 & 15;
            int beg = rowptr[node], end = rowptr[node + 1];
            float4 acc = make_float4(0.f, 0.f, 0.f, 0.f);
            for (int k = beg; k < end; ++k) {
                int2 ep = edgep[k];
                if (flags && !flags[ep.x]) continue;
                float a = __int_as_float(ep.y);
                float4 v = *(const float4*)(hin + (size_t)ep.x * 64 + l * 4);
                acc.x = fmaf(a, v.x, acc.x);
                acc.y = fmaf(a, v.y, acc.y);
                acc.z = fmaf(a, v.z, acc.z);
                acc.w = fmaf(a, v.w, acc.w);
            }
            *(float4*)(hout + (size_t)node * 64 + l * 4) = acc;
        }
    };
    auto samp_add = [&](const float* h) {
        for (int m2 = tid >> 4; m2 < 48; m2 += TPB / 16) {
            int kind = m2 >> 4, k = m2 & 15;
            int gj = sb + k;
            if (gj < B) {
                int idx = kind == 0 ? users[gj] : kind == 1 ? pos[gj] : neg[gj];
                float4 v = *(const float4*)(h + (size_t)idx * 64 + l16 * 4);
                float* p = &sampT[m2 * 64 + l16 * 4];
                p[0] += v.x; p[1] += v.y; p[2] += v.z; p[3] += v.w;
            }
        }
    };

    // P4: layer 0 (flag-guarded: zero rows of h0 were never written)
    spmm(h0, h1, rowNnz);
    gbar(ctrl, 7);
    // P5: samp += h1 ; layer 1: h1 -> h2
    samp_add(h1);
    spmm(h1, h2, nullptr);
    gbar(ctrl, 8);
    // P6: samp += h2 ; layer 2: h2 -> h1
    samp_add(h2);
    spmm(h2, h1, nullptr);
    gbar(ctrl, 9);
    // P7: samp += h1
    samp_add(h1);
    __syncthreads();

    // Scores from LDS: 16 threads per sample (samples k = tid>>4 < 16)
    {
        int k = tid >> 4;
        float sp = 0.0f;
        int gj = sb + k;
        if (k < 16 && gj < B) {
            float4 u = *(const float4*)(&sampT[(0 * 16 + k) * 64 + l16 * 4]);
            float4 p = *(const float4*)(&sampT[(1 * 16 + k) * 64 + l16 * 4]);
            float4 q = *(const float4*)(&sampT[(2 * 16 + k) * 64 + l16 * 4]);
            float ps = u.x * p.x + u.y * p.y + u.z * p.z + u.w * p.w;
            float ns = u.x * q.x + u.y * q.y + u.z * q.z + u.w * q.w;
            for (int m = 1; m < 16; m <<= 1) {
                ps += __shfl_xor(ps, m);
                ns += __shfl_xor(ns, m);
            }
            if (l16 == 0) {
                float x = (ns - ps) * 0.0625f;  // all_emb = acc/4 -> scale 1/16
                sp = fmaxf(x, 0.0f) + log1pf(expf(-fabsf(x)));
            }
        }
        for (int m = 1; m < 64; m <<= 1) sp += __shfl_xor(sp, m);
        if (lane == 0) shf[wid] = sp;
        __syncthreads();
        if (tid == 0) {
            float tt = 0.0f;
            for (int w = 0; w < NWAVE; ++w) tt += shf[w];
            atomicAdd(spTotal, tt);
        }
    }
    gbar(ctrl, 10);

    if (b == 0 && tid == 0) {
        float bm = (float)B;
        float loss_emb = atomicAdd(spTotal, 0.0f) / bm;
        float reg_loss = 0.5f * atomicAdd(regTotal, 0.0f) / bm * 1e-4f;
        float s0 = s[0];
        float s_loss = 0.5f * s0 * s0 / bm * 1e-4f;
        out[0] = loss_emb + reg_loss + s_loss;
        out[1] = loss_emb;
        out[2] = reg_loss;
        out[3] = s_loss;
    }
}

// ---------------------------------------------------------------------------
extern "C" void kernel_launch(void* const* d_in, const int* in_sizes, int n_in,
                              void* d_out, int out_size, void* d_ws, size_t ws_size,
                              hipStream_t stream) {
    const float* weight = (const float*)d_in[0];
    const float* s      = (const float*)d_in[1];
    const int*   src    = (const int*)d_in[2];
    const int*   dst    = (const int*)d_in[3];
    const int*   users  = (const int*)d_in[4];
    const int*   pos    = (const int*)d_in[5];
    const int*   neg    = (const int*)d_in[6];

    const int D = 64;
    const int N = in_sizes[0] / D;
    const int E = in_sizes[2];
    const int B = in_sizes[4];

    char* wp = (char*)d_ws;
    auto alloc = [&](size_t bytes) -> void* {
        void* p = (void*)wp;
        wp += (bytes + 255) & ~(size_t)255;
        return p;
    };
    int*   ctrl     = (int*)alloc(256);
    int*   deg      = (int*)alloc((size_t)N * 4);
    int*   chunkSums= (int*)alloc((size_t)4096 * 4);
    int*   rowptr   = (int*)alloc((size_t)(N + 1) * 4);
    int*   cursor   = (int*)alloc((size_t)N * 4);
    float* dinv     = (float*)alloc((size_t)N * 4);
    int*   rowNnz   = (int*)alloc((size_t)N * 4);
    int2*  edgep    = (int2*)alloc((size_t)E * 8);
    float* h0       = (float*)alloc((size_t)N * D * 4);
    float* h1       = (float*)alloc((size_t)N * D * 4);
    float* h2       = (float*)alloc((size_t)N * D * 4);

    hipMemsetAsync(ctrl, 0, 256, stream);
    k_mega<<<NBLK, TPB, 0, stream>>>(weight, s, src, dst, users, pos, neg,
                                     ctrl, deg, chunkSums, rowptr, cursor, dinv,
                                     edgep, h0, h1, h2, rowNnz,
                                     (float*)d_out, N, E, B);
}

// Round 8
// 17.869 us; speedup vs baseline: 3.3710x; 1.8033x over previous
//
#include <hip/hip_runtime.h>
#include <math.h>

#define CDIV(a,b) (((a)+(b)-1)/(b))
#define NBLK 256     // k_rest grid: <= CU count -> co-resident -> grid barrier safe
#define TPB  1024
#define NWAVE (TPB / 64)
#define SCAN_BLOCKS 2048
#define SCAN_TPB 256

// ctrl layout (int index), zeroed per call:
//   [0..15] barrier counters   [16] nnzTotal (int)   [18] spTotal (float)

__device__ inline void gbar(int* __restrict__ cnts, int k) {
    __syncthreads();
    if (threadIdx.x == 0) {
        __threadfence();
        atomicAdd(&cnts[k], 1);
        while (atomicAdd(&cnts[k], 0) < NBLK) __builtin_amdgcn_s_sleep(2);
        __threadfence();
    }
    __syncthreads();
}

// ---------------------------------------------------------------------------
// k_scan: high-occupancy streaming pass. Soft-threshold all rows (write h0 +
// rowNnz only for nonzero rows), count nonzero rows (atomic only if block
// count > 0), reg-loss partial -> per-block slot (no atomics).
__global__ __launch_bounds__(SCAN_TPB) void k_scan(
    const float* __restrict__ weight, const float* __restrict__ s,
    const int* __restrict__ users, const int* __restrict__ pos,
    const int* __restrict__ neg,
    float* __restrict__ h0, int* __restrict__ rowNnz,
    int* __restrict__ ctrl, float* __restrict__ regSlots,
    int N, int B)
{
    __shared__ int   shi[SCAN_TPB / 64];
    __shared__ float shf[SCAN_TPB / 64];
    const int tid  = threadIdx.x;
    const int lane = tid & 63, wid = tid >> 6;
    const int gsize = SCAN_BLOCKS * SCAN_TPB;
    const int gtid  = blockIdx.x * SCAN_TPB + tid;
    const float t  = 1.0f / (1.0f + expf(-s[0]));
    const float4* __restrict__ wf4  = (const float4*)weight;
    float4* __restrict__       h0f4 = (float4*)h0;

    int   nzc = 0;
    float ss  = 0.0f;

    // A1: threshold scan over N*16 float4 elements (row = 16 consecutive f4)
    {
        const int total = N * 16;
        const int grp16 = (lane >> 4) << 4;
        auto proc = [&](int idx, float4 v) {
            float4 r;
            r.x = copysignf(fmaxf(fabsf(v.x) - t, 0.0f), v.x);
            r.y = copysignf(fmaxf(fabsf(v.y) - t, 0.0f), v.y);
            r.z = copysignf(fmaxf(fabsf(v.z) - t, 0.0f), v.z);
            r.w = copysignf(fmaxf(fabsf(v.w) - t, 0.0f), v.w);
            int nzl = (r.x != 0.0f) | (r.y != 0.0f) | (r.z != 0.0f) | (r.w != 0.0f);
            unsigned long long m = __ballot(nzl);
            int rowm = (int)((m >> grp16) & 0xFFFFull);   // row-uniform
            if (rowm) {
                h0f4[idx] = r;
                if ((idx & 15) == 0) { rowNnz[idx >> 4] = 1; nzc++; }
            }
        };
        int idx = gtid;
        while (idx + 3 * gsize < total) {
            float4 a0 = wf4[idx];
            float4 a1 = wf4[idx + gsize];
            float4 a2 = wf4[idx + 2 * gsize];
            float4 a3 = wf4[idx + 3 * gsize];
            proc(idx, a0); proc(idx + gsize, a1);
            proc(idx + 2 * gsize, a2); proc(idx + 3 * gsize, a3);
            idx += 4 * gsize;
        }
        while (idx < total) { float4 a0 = wf4[idx]; proc(idx, a0); idx += gsize; }
    }

    // A2: reg-loss gather over sampled rows
    {
        const int tot = 3 * B * 16;
        for (int g2 = gtid; g2 < tot; g2 += gsize) {
            int j = g2 >> 4, l16 = g2 & 15;
            int idx = (j < B) ? users[j] : ((j < 2 * B) ? pos[j - B] : neg[j - 2 * B]);
            float4 e = *(const float4*)(weight + (size_t)idx * 64 + l16 * 4);
            ss += e.x * e.x + e.y * e.y + e.z * e.z + e.w * e.w;
        }
    }

    for (int m = 1; m < 64; m <<= 1) {
        nzc += __shfl_xor(nzc, m);
        ss  += __shfl_xor(ss, m);
    }
    if (lane == 0) { shi[wid] = nzc; shf[wid] = ss; }
    __syncthreads();
    if (tid == 0) {
        int   a = 0; float f = 0.0f;
        for (int i = 0; i < SCAN_TPB / 64; ++i) { a += shi[i]; f += shf[i]; }
        if (a) atomicAdd(ctrl + 16, a);      // zero atomics in the gated case
        regSlots[blockIdx.x] = f;
    }
}

// ---------------------------------------------------------------------------
// k_rest: gate -> either finalize (gated) or full CSR + 3xSpMM pipeline.
__global__ __launch_bounds__(TPB) void k_rest(
    const float* __restrict__ weight, const float* __restrict__ s,
    const int* __restrict__ src, const int* __restrict__ dst,
    const int* __restrict__ users, const int* __restrict__ pos,
    const int* __restrict__ neg,
    int* __restrict__ ctrl, const float* __restrict__ regSlots,
    int* __restrict__ deg, int* __restrict__ chunkSums,
    int* __restrict__ rowptr, int* __restrict__ cursor, float* __restrict__ dinv,
    int2* __restrict__ edgep, const float* __restrict__ h0,
    float* __restrict__ h1, float* __restrict__ h2,
    const int* __restrict__ rowNnz,
    float* __restrict__ out, int N, int E, int B)
{
    __shared__ float sampT[48 * 64];
    __shared__ int   shi[NWAVE];
    __shared__ float shf[NWAVE];
    const int tid  = threadIdx.x;
    const int b    = blockIdx.x;
    const int lane = tid & 63, wid = tid >> 6;
    const int gsize = NBLK * TPB;
    const int gtid  = b * TPB + tid;
    const float t  = 1.0f / (1.0f + expf(-s[0]));
    float* spTotal = (float*)(ctrl + 18);

    const int gate = ctrl[16];   // k_scan completed: device-visible

    // helper: block-0 sum of regSlots[SCAN_BLOCKS]
    auto reg_sum_b0 = [&]() -> float {
        float r = 0.0f;
        for (int i = tid; i < SCAN_BLOCKS; i += TPB) r += regSlots[i];
        for (int m = 1; m < 64; m <<= 1) r += __shfl_xor(r, m);
        if (lane == 0) shf[wid] = r;
        __syncthreads();
        float tt = 0.0f;
        for (int w = 0; w < NWAVE; ++w) tt += shf[w];
        return tt;
    };

    if (gate == 0) {
        // sparse_v == 0 everywhere -> scores 0 -> loss_emb = ln 2 exactly.
        if (b == 0) {
            float reg_sum = reg_sum_b0();
            if (tid == 0) {
                float bm = (float)B;
                float loss_emb = 0.69314718056f;
                float reg_loss = 0.5f * reg_sum / bm * 1e-4f;
                float s0 = s[0];
                float s_loss = 0.5f * s0 * s0 / bm * 1e-4f;
                out[0] = loss_emb + reg_loss + s_loss;
                out[1] = loss_emb;
                out[2] = reg_loss;
                out[3] = s_loss;
            }
        }
        return;
    }

    // ======================= nnz > 0 path ==================================
    const int sb = b * 16;
    const int l16 = tid & 15;

    // samp tile init in LDS (recompute threshold rows): 0..15=u,16..31=p,32..47=n
    for (int m2 = tid >> 4; m2 < 48; m2 += TPB / 16) {
        int kind = m2 >> 4, k = m2 & 15;
        int gj = sb + k;
        float4 rr = make_float4(0.f, 0.f, 0.f, 0.f);
        if (gj < B) {
            int idx = kind == 0 ? users[gj] : kind == 1 ? pos[gj] : neg[gj];
            float4 e = *(const float4*)(weight + (size_t)idx * 64 + l16 * 4);
            rr.x = copysignf(fmaxf(fabsf(e.x) - t, 0.0f), e.x);
            rr.y = copysignf(fmaxf(fabsf(e.y) - t, 0.0f), e.y);
            rr.z = copysignf(fmaxf(fabsf(e.z) - t, 0.0f), e.z);
            rr.w = copysignf(fmaxf(fabsf(e.w) - t, 0.0f), e.w);
        }
        *(float4*)(&sampT[m2 * 64 + l16 * 4]) = rr;
    }

    // P0: zero in-degree
    for (int i = gtid; i < N; i += gsize) deg[i] = 0;
    gbar(ctrl, 1);
    // P1: histogram
    for (int e = gtid; e < E; e += gsize) atomicAdd(&deg[dst[e]], 1);
    gbar(ctrl, 2);

    // P2a: per-chunk sums (chunk = 4096 = 1024 thr x 4)
    const int nchunk = (N + 4095) >> 12;
    for (int c = b; c < nchunk; c += NBLK) {
        int base = (c << 12) + tid * 4;
        int sum = 0;
        if (base + 3 < N) {
            int4 v = *(const int4*)(deg + base);
            sum = v.x + v.y + v.z + v.w;
        } else {
            for (int k = 0; k < 4; ++k) if (base + k < N) sum += deg[base + k];
        }
        for (int m = 1; m < 64; m <<= 1) sum += __shfl_xor(sum, m);
        __syncthreads();
        if (lane == 0) shi[wid] = sum;
        __syncthreads();
        if (tid == 0) {
            int tt = 0;
            for (int w = 0; w < NWAVE; ++w) tt += shi[w];
            chunkSums[c] = tt;
        }
        __syncthreads();
    }
    gbar(ctrl, 3);

    // P2b: block 0 exclusive-scans chunkSums; rowptr[N] = total
    if (b == 0) {
        int c0 = tid * 4;
        int a0 = (c0 + 0 < nchunk) ? chunkSums[c0 + 0] : 0;
        int a1 = (c0 + 1 < nchunk) ? chunkSums[c0 + 1] : 0;
        int a2 = (c0 + 2 < nchunk) ? chunkSums[c0 + 2] : 0;
        int a3 = (c0 + 3 < nchunk) ? chunkSums[c0 + 3] : 0;
        int tot = a0 + a1 + a2 + a3;
        int incl = tot;
        for (int off = 1; off < 64; off <<= 1) {
            int tt = __shfl_up(incl, off);
            if (lane >= off) incl += tt;
        }
        __syncthreads();
        if (lane == 63) shi[wid] = incl;
        __syncthreads();
        int wp = 0;
        for (int w = 0; w < wid; ++w) wp += shi[w];
        int excl = wp + incl - tot;
        if (c0 + 0 < nchunk) chunkSums[c0 + 0] = excl;
        if (c0 + 1 < nchunk) chunkSums[c0 + 1] = excl + a0;
        if (c0 + 2 < nchunk) chunkSums[c0 + 2] = excl + a0 + a1;
        if (c0 + 3 < nchunk) chunkSums[c0 + 3] = excl + a0 + a1 + a2;
        if (tid == 0) {
            int tt = 0;
            for (int w = 0; w < NWAVE; ++w) tt += shi[w];
            rowptr[N] = tt;
        }
    }
    gbar(ctrl, 4);

    // P2c: per-chunk local scan + chunk offset -> rowptr, cursor, dinv
    for (int c = b; c < nchunk; c += NBLK) {
        int base = (c << 12) + tid * 4;
        int v0 = 0, v1 = 0, v2 = 0, v3 = 0;
        if (base + 3 < N) {
            int4 v = *(const int4*)(deg + base);
            v0 = v.x; v1 = v.y; v2 = v.z; v3 = v.w;
        } else {
            if (base + 0 < N) v0 = deg[base + 0];
            if (base + 1 < N) v1 = deg[base + 1];
            if (base + 2 < N) v2 = deg[base + 2];
        }
        int tot = v0 + v1 + v2 + v3;
        int incl = tot;
        for (int off = 1; off < 64; off <<= 1) {
            int tt = __shfl_up(incl, off);
            if (lane >= off) incl += tt;
        }
        __syncthreads();
        if (lane == 63) shi[wid] = incl;
        __syncthreads();
        int wp = 0;
        for (int w = 0; w < wid; ++w) wp += shi[w];
        int excl = chunkSums[c] + wp + incl - tot;
        int e0 = excl, e1 = e0 + v0, e2 = e1 + v1, e3 = e2 + v2;
        if (base + 0 < N) { rowptr[base+0] = e0; cursor[base+0] = e0; dinv[base+0] = v0 > 0 ? rsqrtf((float)v0) : 0.f; }
        if (base + 1 < N) { rowptr[base+1] = e1; cursor[base+1] = e1; dinv[base+1] = v1 > 0 ? rsqrtf((float)v1) : 0.f; }
        if (base + 2 < N) { rowptr[base+2] = e2; cursor[base+2] = e2; dinv[base+2] = v2 > 0 ? rsqrtf((float)v2) : 0.f; }
        if (base + 3 < N) { rowptr[base+3] = e3; cursor[base+3] = e3; dinv[base+3] = v3 > 0 ? rsqrtf((float)v3) : 0.f; }
        __syncthreads();
    }
    gbar(ctrl, 5);

    // P3: scatter edges into CSR order; payload packed 8B = (src, adj)
    for (int e = gtid; e < E; e += gsize) {
        int d = dst[e], sN = src[e];
        int k = atomicAdd(&cursor[d], 1);
        edgep[k] = make_int2(sN, __float_as_int(dinv[sN] * dinv[d]));
    }
    gbar(ctrl, 6);

    auto spmm = [&](const float* hin, float* hout, const int* flags) {
        for (int g2 = gtid; g2 < N * 16; g2 += gsize) {
            int node = g2 >> 4, l = g2 & 15;
            int beg = rowptr[node], end = rowptr[node + 1];
            float4 acc = make_float4(0.f, 0.f, 0.f, 0.f);
            for (int k = beg; k < end; ++k) {
                int2 ep = edgep[k];
                if (flags && !flags[ep.x]) continue;
                float a = __int_as_float(ep.y);
                float4 v = *(const float4*)(hin + (size_t)ep.x * 64 + l * 4);
                acc.x = fmaf(a, v.x, acc.x);
                acc.y = fmaf(a, v.y, acc.y);
                acc.z = fmaf(a, v.z, acc.z);
                acc.w = fmaf(a, v.w, acc.w);
            }
            *(float4*)(hout + (size_t)node * 64 + l * 4) = acc;
        }
    };
    auto samp_add = [&](const float* h) {
        for (int m2 = tid >> 4; m2 < 48; m2 += TPB / 16) {
            int kind = m2 >> 4, k = m2 & 15;
            int gj = sb + k;
            if (gj < B) {
                int idx = kind == 0 ? users[gj] : kind == 1 ? pos[gj] : neg[gj];
                float4 v = *(const float4*)(h + (size_t)idx * 64 + l16 * 4);
                float* p = &sampT[m2 * 64 + l16 * 4];
                p[0] += v.x; p[1] += v.y; p[2] += v.z; p[3] += v.w;
            }
        }
    };

    // P4..P7: 3 SpMM layers with sampled-row accumulation
    spmm(h0, h1, rowNnz);
    gbar(ctrl, 7);
    samp_add(h1);
    spmm(h1, h2, nullptr);
    gbar(ctrl, 8);
    samp_add(h2);
    spmm(h2, h1, nullptr);
    gbar(ctrl, 9);
    samp_add(h1);
    __syncthreads();

    // Scores from LDS: 16 threads per sample (k = tid>>4 < 16)
    {
        int k = tid >> 4;
        float sp = 0.0f;
        int gj = sb + k;
        if (k < 16 && gj < B) {
            float4 u = *(const float4*)(&sampT[(0 * 16 + k) * 64 + l16 * 4]);
            float4 p = *(const float4*)(&sampT[(1 * 16 + k) * 64 + l16 * 4]);
            float4 q = *(const float4*)(&sampT[(2 * 16 + k) * 64 + l16 * 4]);
            float ps = u.x * p.x + u.y * p.y + u.z * p.z + u.w * p.w;
            float ns = u.x * q.x + u.y * q.y + u.z * q.z + u.w * q.w;
            for (int m = 1; m < 16; m <<= 1) {
                ps += __shfl_xor(ps, m);
                ns += __shfl_xor(ns, m);
            }
            if (l16 == 0) {
                float x = (ns - ps) * 0.0625f;  // all_emb = acc/4 -> scale 1/16
                sp = fmaxf(x, 0.0f) + log1pf(expf(-fabsf(x)));
            }
        }
        for (int m = 1; m < 64; m <<= 1) sp += __shfl_xor(sp, m);
        if (lane == 0) shf[wid] = sp;
        __syncthreads();
        if (tid == 0) {
            float tt = 0.0f;
            for (int w = 0; w < NWAVE; ++w) tt += shf[w];
            atomicAdd(spTotal, tt);
        }
    }
    gbar(ctrl, 10);

    if (b == 0) {
        __syncthreads();
        float reg_sum = reg_sum_b0();
        if (tid == 0) {
            float bm = (float)B;
            float loss_emb = atomicAdd(spTotal, 0.0f) / bm;
            float reg_loss = 0.5f * reg_sum / bm * 1e-4f;
            float s0 = s[0];
            float s_loss = 0.5f * s0 * s0 / bm * 1e-4f;
            out[0] = loss_emb + reg_loss + s_loss;
            out[1] = loss_emb;
            out[2] = reg_loss;
            out[3] = s_loss;
        }
    }
}

// ---------------------------------------------------------------------------
extern "C" void kernel_launch(void* const* d_in, const int* in_sizes, int n_in,
                              void* d_out, int out_size, void* d_ws, size_t ws_size,
                              hipStream_t stream) {
    const float* weight = (const float*)d_in[0];
    const float* s      = (const float*)d_in[1];
    const int*   src    = (const int*)d_in[2];
    const int*   dst    = (const int*)d_in[3];
    const int*   users  = (const int*)d_in[4];
    const int*   pos    = (const int*)d_in[5];
    const int*   neg    = (const int*)d_in[6];

    const int D = 64;
    const int N = in_sizes[0] / D;
    const int E = in_sizes[2];
    const int B = in_sizes[4];

    char* wp = (char*)d_ws;
    auto alloc = [&](size_t bytes) -> void* {
        void* p = (void*)wp;
        wp += (bytes + 255) & ~(size_t)255;
        return p;
    };
    int*   ctrl     = (int*)alloc(256);
    float* regSlots = (float*)alloc((size_t)SCAN_BLOCKS * 4);
    int*   rowNnz   = (int*)alloc((size_t)N * 4);
    int*   deg      = (int*)alloc((size_t)N * 4);
    int*   chunkSums= (int*)alloc((size_t)4096 * 4);
    int*   rowptr   = (int*)alloc((size_t)(N + 1) * 4);
    int*   cursor   = (int*)alloc((size_t)N * 4);
    float* dinv     = (float*)alloc((size_t)N * 4);
    int2*  edgep    = (int2*)alloc((size_t)E * 8);
    float* h0       = (float*)alloc((size_t)N * D * 4);
    float* h1       = (float*)alloc((size_t)N * D * 4);
    float* h2       = (float*)alloc((size_t)N * D * 4);

    hipMemsetAsync(ctrl, 0, 256, stream);
    hipMemsetAsync(rowNnz, 0, (size_t)N * 4, stream);
    k_scan<<<SCAN_BLOCKS, SCAN_TPB, 0, stream>>>(weight, s, users, pos, neg,
                                                 h0, rowNnz, ctrl, regSlots, N, B);
    k_rest<<<NBLK, TPB, 0, stream>>>(weight, s, src, dst, users, pos, neg,
                                     ctrl, regSlots, deg, chunkSums, rowptr,
                                     cursor, dinv, edgep, h0, h1, h2, rowNnz,
                                     (float*)d_out, N, E, B);
}

// Round 9
// 12.515 us; speedup vs baseline: 4.8128x; 1.4277x over previous
//
#include <hip/hip_runtime.h>
#include <math.h>

#define CDIV(a,b) (((a)+(b)-1)/(b))
#define NBLK 256     // k_rest grid: <= CU count -> co-resident -> grid barrier safe
#define TPB  1024
#define NWAVE (TPB / 64)
#define SCAN_BLOCKS 2048
#define SCAN_TPB 256

// ctrl layout (int index), zeroed by k_scan block 0 each call (ctrl is consumed
// only by k_rest, which launches strictly after k_scan completes):
//   [0..15] barrier counters   [18] spTotal (float)

__device__ inline void gbar(int* __restrict__ cnts, int k) {
    __syncthreads();
    if (threadIdx.x == 0) {
        __threadfence();
        atomicAdd(&cnts[k], 1);
        while (atomicAdd(&cnts[k], 0) < NBLK) __builtin_amdgcn_s_sleep(2);
        __threadfence();
    }
    __syncthreads();
}

// ---------------------------------------------------------------------------
// k_scan: high-occupancy streaming pass. Soft-threshold all rows: write h0
// only for nonzero rows, rowNnz unconditionally (0/1), per-block nnz and
// reg-loss partials into slots (no atomics, no pre-zeroed state anywhere).
__global__ __launch_bounds__(SCAN_TPB) void k_scan(
    const float* __restrict__ weight, const float* __restrict__ s,
    const int* __restrict__ users, const int* __restrict__ pos,
    const int* __restrict__ neg,
    float* __restrict__ h0, int* __restrict__ rowNnz,
    int* __restrict__ ctrl, int* __restrict__ nnzSlots,
    float* __restrict__ regSlots, int N, int B)
{
    __shared__ int   shi[SCAN_TPB / 64];
    __shared__ float shf[SCAN_TPB / 64];
    const int tid  = threadIdx.x;
    const int lane = tid & 63, wid = tid >> 6;
    const int gsize = SCAN_BLOCKS * SCAN_TPB;
    const int gtid  = blockIdx.x * SCAN_TPB + tid;
    const float t  = 1.0f / (1.0f + expf(-s[0]));
    const float4* __restrict__ wf4  = (const float4*)weight;
    float4* __restrict__       h0f4 = (float4*)h0;

    if (blockIdx.x == 0 && tid < 64) ctrl[tid] = 0;   // ctrl used only by k_rest

    int   nzc = 0;
    float ss  = 0.0f;

    // A1: threshold scan over N*16 float4 elements (row = 16 consecutive f4)
    {
        const int total = N * 16;
        const int grp16 = (lane >> 4) << 4;
        auto proc = [&](int idx, float4 v) {
            float4 r;
            r.x = copysignf(fmaxf(fabsf(v.x) - t, 0.0f), v.x);
            r.y = copysignf(fmaxf(fabsf(v.y) - t, 0.0f), v.y);
            r.z = copysignf(fmaxf(fabsf(v.z) - t, 0.0f), v.z);
            r.w = copysignf(fmaxf(fabsf(v.w) - t, 0.0f), v.w);
            int nzl = (r.x != 0.0f) | (r.y != 0.0f) | (r.z != 0.0f) | (r.w != 0.0f);
            unsigned long long m = __ballot(nzl);
            int rowm = (int)((m >> grp16) & 0xFFFFull);   // row-uniform
            if (rowm) h0f4[idx] = r;                      // zero rows never read
            if ((idx & 15) == 0) { rowNnz[idx >> 4] = (rowm != 0); nzc += (rowm != 0); }
        };
        int idx = gtid;
        while (idx + 3 * gsize < total) {
            float4 a0 = wf4[idx];
            float4 a1 = wf4[idx + gsize];
            float4 a2 = wf4[idx + 2 * gsize];
            float4 a3 = wf4[idx + 3 * gsize];
            proc(idx, a0); proc(idx + gsize, a1);
            proc(idx + 2 * gsize, a2); proc(idx + 3 * gsize, a3);
            idx += 4 * gsize;
        }
        while (idx < total) { float4 a0 = wf4[idx]; proc(idx, a0); idx += gsize; }
    }

    // A2: reg-loss gather over sampled rows
    {
        const int tot = 3 * B * 16;
        for (int g2 = gtid; g2 < tot; g2 += gsize) {
            int j = g2 >> 4, l16 = g2 & 15;
            int idx = (j < B) ? users[j] : ((j < 2 * B) ? pos[j - B] : neg[j - 2 * B]);
            float4 e = *(const float4*)(weight + (size_t)idx * 64 + l16 * 4);
            ss += e.x * e.x + e.y * e.y + e.z * e.z + e.w * e.w;
        }
    }

    for (int m = 1; m < 64; m <<= 1) {
        nzc += __shfl_xor(nzc, m);
        ss  += __shfl_xor(ss, m);
    }
    if (lane == 0) { shi[wid] = nzc; shf[wid] = ss; }
    __syncthreads();
    if (tid == 0) {
        int   a = 0; float f = 0.0f;
        for (int i = 0; i < SCAN_TPB / 64; ++i) { a += shi[i]; f += shf[i]; }
        nnzSlots[blockIdx.x] = a;
        regSlots[blockIdx.x] = f;
    }
}

// ---------------------------------------------------------------------------
// k_rest: per-block gate from nnzSlots -> either finalize (gated, block 0) or
// run the full CSR + 3xSpMM pipeline behind hand-rolled grid barriers.
__global__ __launch_bounds__(TPB) void k_rest(
    const float* __restrict__ weight, const float* __restrict__ s,
    const int* __restrict__ src, const int* __restrict__ dst,
    const int* __restrict__ users, const int* __restrict__ pos,
    const int* __restrict__ neg,
    int* __restrict__ ctrl, const int* __restrict__ nnzSlots,
    const float* __restrict__ regSlots,
    int* __restrict__ deg, int* __restrict__ chunkSums,
    int* __restrict__ rowptr, int* __restrict__ cursor, float* __restrict__ dinv,
    int2* __restrict__ edgep, const float* __restrict__ h0,
    float* __restrict__ h1, float* __restrict__ h2,
    const int* __restrict__ rowNnz,
    float* __restrict__ out, int N, int E, int B)
{
    __shared__ float sampT[48 * 64];
    __shared__ int   shi[NWAVE];
    __shared__ float shf[NWAVE];
    const int tid  = threadIdx.x;
    const int b    = blockIdx.x;
    const int lane = tid & 63, wid = tid >> 6;
    const int gsize = NBLK * TPB;
    const int gtid  = b * TPB + tid;
    const float t  = 1.0f / (1.0f + expf(-s[0]));
    float* spTotal = (float*)(ctrl + 18);

    // gate = sum(nnzSlots) — every block computes it (8 KB, L2-resident)
    int gate;
    {
        int a = 0;
        for (int i = tid; i < SCAN_BLOCKS; i += TPB) a += nnzSlots[i];
        for (int m = 1; m < 64; m <<= 1) a += __shfl_xor(a, m);
        if (lane == 0) shi[wid] = a;
        __syncthreads();
        int tt = 0;
        for (int w = 0; w < NWAVE; ++w) tt += shi[w];
        gate = tt;
        __syncthreads();
    }

    // helper: block-local sum of regSlots[SCAN_BLOCKS]
    auto reg_sum_blk = [&]() -> float {
        float r = 0.0f;
        for (int i = tid; i < SCAN_BLOCKS; i += TPB) r += regSlots[i];
        for (int m = 1; m < 64; m <<= 1) r += __shfl_xor(r, m);
        if (lane == 0) shf[wid] = r;
        __syncthreads();
        float tt = 0.0f;
        for (int w = 0; w < NWAVE; ++w) tt += shf[w];
        return tt;
    };

    if (gate == 0) {
        // sparse_v == 0 everywhere -> scores 0 -> loss_emb = ln 2 exactly.
        if (b == 0) {
            float reg_sum = reg_sum_blk();
            if (tid == 0) {
                float bm = (float)B;
                float loss_emb = 0.69314718056f;
                float reg_loss = 0.5f * reg_sum / bm * 1e-4f;
                float s0 = s[0];
                float s_loss = 0.5f * s0 * s0 / bm * 1e-4f;
                out[0] = loss_emb + reg_loss + s_loss;
                out[1] = loss_emb;
                out[2] = reg_loss;
                out[3] = s_loss;
            }
        }
        return;
    }

    // ======================= nnz > 0 path ==================================
    const int sb = b * 16;
    const int l16 = tid & 15;

    // samp tile init in LDS (recompute threshold rows): 0..15=u,16..31=p,32..47=n
    for (int m2 = tid >> 4; m2 < 48; m2 += TPB / 16) {
        int kind = m2 >> 4, k = m2 & 15;
        int gj = sb + k;
        float4 rr = make_float4(0.f, 0.f, 0.f, 0.f);
        if (gj < B) {
            int idx = kind == 0 ? users[gj] : kind == 1 ? pos[gj] : neg[gj];
            float4 e = *(const float4*)(weight + (size_t)idx * 64 + l16 * 4);
            rr.x = copysignf(fmaxf(fabsf(e.x) - t, 0.0f), e.x);
            rr.y = copysignf(fmaxf(fabsf(e.y) - t, 0.0f), e.y);
            rr.z = copysignf(fmaxf(fabsf(e.z) - t, 0.0f), e.z);
            rr.w = copysignf(fmaxf(fabsf(e.w) - t, 0.0f), e.w);
        }
        *(float4*)(&sampT[m2 * 64 + l16 * 4]) = rr;
    }

    // P0: zero in-degree
    for (int i = gtid; i < N; i += gsize) deg[i] = 0;
    gbar(ctrl, 1);
    // P1: histogram
    for (int e = gtid; e < E; e += gsize) atomicAdd(&deg[dst[e]], 1);
    gbar(ctrl, 2);

    // P2a: per-chunk sums (chunk = 4096 = 1024 thr x 4)
    const int nchunk = (N + 4095) >> 12;
    for (int c = b; c < nchunk; c += NBLK) {
        int base = (c << 12) + tid * 4;
        int sum = 0;
        if (base + 3 < N) {
            int4 v = *(const int4*)(deg + base);
            sum = v.x + v.y + v.z + v.w;
        } else {
            for (int k = 0; k < 4; ++k) if (base + k < N) sum += deg[base + k];
        }
        for (int m = 1; m < 64; m <<= 1) sum += __shfl_xor(sum, m);
        __syncthreads();
        if (lane == 0) shi[wid] = sum;
        __syncthreads();
        if (tid == 0) {
            int tt = 0;
            for (int w = 0; w < NWAVE; ++w) tt += shi[w];
            chunkSums[c] = tt;
        }
        __syncthreads();
    }
    gbar(ctrl, 3);

    // P2b: block 0 exclusive-scans chunkSums; rowptr[N] = total
    if (b == 0) {
        int c0 = tid * 4;
        int a0 = (c0 + 0 < nchunk) ? chunkSums[c0 + 0] : 0;
        int a1 = (c0 + 1 < nchunk) ? chunkSums[c0 + 1] : 0;
        int a2 = (c0 + 2 < nchunk) ? chunkSums[c0 + 2] : 0;
        int a3 = (c0 + 3 < nchunk) ? chunkSums[c0 + 3] : 0;
        int tot = a0 + a1 + a2 + a3;
        int incl = tot;
        for (int off = 1; off < 64; off <<= 1) {
            int tt = __shfl_up(incl, off);
            if (lane >= off) incl += tt;
        }
        __syncthreads();
        if (lane == 63) shi[wid] = incl;
        __syncthreads();
        int wp = 0;
        for (int w = 0; w < wid; ++w) wp += shi[w];
        int excl = wp + incl - tot;
        if (c0 + 0 < nchunk) chunkSums[c0 + 0] = excl;
        if (c0 + 1 < nchunk) chunkSums[c0 + 1] = excl + a0;
        if (c0 + 2 < nchunk) chunkSums[c0 + 2] = excl + a0 + a1;
        if (c0 + 3 < nchunk) chunkSums[c0 + 3] = excl + a0 + a1 + a2;
        if (tid == 0) {
            int tt = 0;
            for (int w = 0; w < NWAVE; ++w) tt += shi[w];
            rowptr[N] = tt;
        }
    }
    gbar(ctrl, 4);

    // P2c: per-chunk local scan + chunk offset -> rowptr, cursor, dinv
    for (int c = b; c < nchunk; c += NBLK) {
        int base = (c << 12) + tid * 4;
        int v0 = 0, v1 = 0, v2 = 0, v3 = 0;
        if (base + 3 < N) {
            int4 v = *(const int4*)(deg + base);
            v0 = v.x; v1 = v.y; v2 = v.z; v3 = v.w;
        } else {
            if (base + 0 < N) v0 = deg[base + 0];
            if (base + 1 < N) v1 = deg[base + 1];
            if (base + 2 < N) v2 = deg[base + 2];
        }
        int tot = v0 + v1 + v2 + v3;
        int incl = tot;
        for (int off = 1; off < 64; off <<= 1) {
            int tt = __shfl_up(incl, off);
            if (lane >= off) incl += tt;
        }
        __syncthreads();
        if (lane == 63) shi[wid] = incl;
        __syncthreads();
        int wp = 0;
        for (int w = 0; w < wid; ++w) wp += shi[w];
        int excl = chunkSums[c] + wp + incl - tot;
        int e0 = excl, e1 = e0 + v0, e2 = e1 + v1, e3 = e2 + v2;
        if (base + 0 < N) { rowptr[base+0] = e0; cursor[base+0] = e0; dinv[base+0] = v0 > 0 ? rsqrtf((float)v0) : 0.f; }
        if (base + 1 < N) { rowptr[base+1] = e1; cursor[base+1] = e1; dinv[base+1] = v1 > 0 ? rsqrtf((float)v1) : 0.f; }
        if (base + 2 < N) { rowptr[base+2] = e2; cursor[base+2] = e2; dinv[base+2] = v2 > 0 ? rsqrtf((float)v2) : 0.f; }
        if (base + 3 < N) { rowptr[base+3] = e3; cursor[base+3] = e3; dinv[base+3] = v3 > 0 ? rsqrtf((float)v3) : 0.f; }
        __syncthreads();
    }
    gbar(ctrl, 5);

    // P3: scatter edges into CSR order; payload packed 8B = (src, adj)
    for (int e = gtid; e < E; e += gsize) {
        int d = dst[e], sN = src[e];
        int k = atomicAdd(&cursor[d], 1);
        edgep[k] = make_int2(sN, __float_as_int(dinv[sN] * dinv[d]));
    }
    gbar(ctrl, 6);

    auto spmm = [&](const float* hin, float* hout, const int* flags) {
        for (int g2 = gtid; g2 < N * 16; g2 += gsize) {
            int node = g2 >> 4, l = g2 & 15;
            int beg = rowptr[node], end = rowptr[node + 1];
            float4 acc = make_float4(0.f, 0.f, 0.f, 0.f);
            for (int k = beg; k < end; ++k) {
                int2 ep = edgep[k];
                if (flags && !flags[ep.x]) continue;
                float a = __int_as_float(ep.y);
                float4 v = *(const float4*)(hin + (size_t)ep.x * 64 + l * 4);
                acc.x = fmaf(a, v.x, acc.x);
                acc.y = fmaf(a, v.y, acc.y);
                acc.z = fmaf(a, v.z, acc.z);
                acc.w = fmaf(a, v.w, acc.w);
            }
            *(float4*)(hout + (size_t)node * 64 + l * 4) = acc;
        }
    };
    auto samp_add = [&](const float* h) {
        for (int m2 = tid >> 4; m2 < 48; m2 += TPB / 16) {
            int kind = m2 >> 4, k = m2 & 15;
            int gj = sb + k;
            if (gj < B) {
                int idx = kind == 0 ? users[gj] : kind == 1 ? pos[gj] : neg[gj];
                float4 v = *(const float4*)(h + (size_t)idx * 64 + l16 * 4);
                float* p = &sampT[m2 * 64 + l16 * 4];
                p[0] += v.x; p[1] += v.y; p[2] += v.z; p[3] += v.w;
            }
        }
    };

    // P4..P7: 3 SpMM layers with sampled-row accumulation
    spmm(h0, h1, rowNnz);
    gbar(ctrl, 7);
    samp_add(h1);
    spmm(h1, h2, nullptr);
    gbar(ctrl, 8);
    samp_add(h2);
    spmm(h2, h1, nullptr);
    gbar(ctrl, 9);
    samp_add(h1);
    __syncthreads();

    // Scores from LDS: 16 threads per sample (k = tid>>4 < 16)
    {
        int k = tid >> 4;
        float sp = 0.0f;
        int gj = sb + k;
        if (k < 16 && gj < B) {
            float4 u = *(const float4*)(&sampT[(0 * 16 + k) * 64 + l16 * 4]);
            float4 p = *(const float4*)(&sampT[(1 * 16 + k) * 64 + l16 * 4]);
            float4 q = *(const float4*)(&sampT[(2 * 16 + k) * 64 + l16 * 4]);
            float ps = u.x * p.x + u.y * p.y + u.z * p.z + u.w * p.w;
            float ns = u.x * q.x + u.y * q.y + u.z * q.z + u.w * q.w;
            for (int m = 1; m < 16; m <<= 1) {
                ps += __shfl_xor(ps, m);
                ns += __shfl_xor(ns, m);
            }
            if (l16 == 0) {
                float x = (ns - ps) * 0.0625f;  // all_emb = acc/4 -> scale 1/16
                sp = fmaxf(x, 0.0f) + log1pf(expf(-fabsf(x)));
            }
        }
        for (int m = 1; m < 64; m <<= 1) sp += __shfl_xor(sp, m);
        if (lane == 0) shf[wid] = sp;
        __syncthreads();
        if (tid == 0) {
            float tt = 0.0f;
            for (int w = 0; w < NWAVE; ++w) tt += shf[w];
            atomicAdd(spTotal, tt);
        }
    }
    gbar(ctrl, 10);

    if (b == 0) {
        __syncthreads();
        float reg_sum = reg_sum_blk();
        if (tid == 0) {
            float bm = (float)B;
            float loss_emb = atomicAdd(spTotal, 0.0f) / bm;
            float reg_loss = 0.5f * reg_sum / bm * 1e-4f;
            float s0 = s[0];
            float s_loss = 0.5f * s0 * s0 / bm * 1e-4f;
            out[0] = loss_emb + reg_loss + s_loss;
            out[1] = loss_emb;
            out[2] = reg_loss;
            out[3] = s_loss;
        }
    }
}

// ---------------------------------------------------------------------------
extern "C" void kernel_launch(void* const* d_in, const int* in_sizes, int n_in,
                              void* d_out, int out_size, void* d_ws, size_t ws_size,
                              hipStream_t stream) {
    const float* weight = (const float*)d_in[0];
    const float* s      = (const float*)d_in[1];
    const int*   src    = (const int*)d_in[2];
    const int*   dst    = (const int*)d_in[3];
    const int*   users  = (const int*)d_in[4];
    const int*   pos    = (const int*)d_in[5];
    const int*   neg    = (const int*)d_in[6];

    const int D = 64;
    const int N = in_sizes[0] / D;
    const int E = in_sizes[2];
    const int B = in_sizes[4];

    char* wp = (char*)d_ws;
    auto alloc = [&](size_t bytes) -> void* {
        void* p = (void*)wp;
        wp += (bytes + 255) & ~(size_t)255;
        return p;
    };
    int*   ctrl     = (int*)alloc(256);
    int*   nnzSlots = (int*)alloc((size_t)SCAN_BLOCKS * 4);
    float* regSlots = (float*)alloc((size_t)SCAN_BLOCKS * 4);
    int*   rowNnz   = (int*)alloc((size_t)N * 4);
    int*   deg      = (int*)alloc((size_t)N * 4);
    int*   chunkSums= (int*)alloc((size_t)4096 * 4);
    int*   rowptr   = (int*)alloc((size_t)(N + 1) * 4);
    int*   cursor   = (int*)alloc((size_t)N * 4);
    float* dinv     = (float*)alloc((size_t)N * 4);
    int2*  edgep    = (int2*)alloc((size_t)E * 8);
    float* h0       = (float*)alloc((size_t)N * D * 4);
    float* h1       = (float*)alloc((size_t)N * D * 4);
    float* h2       = (float*)alloc((size_t)N * D * 4);

    k_scan<<<SCAN_BLOCKS, SCAN_TPB, 0, stream>>>(weight, s, users, pos, neg,
                                                 h0, rowNnz, ctrl, nnzSlots,
                                                 regSlots, N, B);
    k_rest<<<NBLK, TPB, 0, stream>>>(weight, s, src, dst, users, pos, neg,
                                     ctrl, nnzSlots, regSlots, deg, chunkSums,
                                     rowptr, cursor, dinv, edgep, h0, h1, h2,
                                     rowNnz, (float*)d_out, N, E, B);
}